// Round 4
// baseline (131.757 us; speedup 1.0000x reference)
//
#include <hip/hip_runtime.h>

#define NN 50000
#define NE 100000
#define NREL 64
#define D 64
#define BPR 16                               // blocks per relation
#define NPB ((NN + BPR - 1) / BPR)           // nodes scanned per rel-block = 3125
#define LCAP 512
#define SELF_NPB 64                          // nodes per k_self block

typedef unsigned long long u64;

__global__ void k_init(u64* __restrict__ packed) {
    int t = blockIdx.x * blockDim.x + threadIdx.x;
    if (t * 2 + 1 < NN)
        reinterpret_cast<ulonglong2*>(packed)[t] = ulonglong2{0ull, 0ull};
}

// one 64-bit atomicMax per edge: key = (e+1)<<22 | rel<<16 | src
__global__ void k_scatter(const int* __restrict__ edges, u64* __restrict__ packed) {
    int e = blockIdx.x * blockDim.x + threadIdx.x;
    if (e < NE) {
        int s = edges[e * 3 + 0];
        int r = edges[e * 3 + 1];
        int d = edges[e * 3 + 2];
        u64 key = ((u64)(e + 1) << 22) | ((u64)r << 16) | (u64)s;
        atomicMax(&packed[d], key);
    }
}

__device__ __forceinline__ float bcast(float x, int i) {
    return __int_as_float(__builtin_amdgcn_readlane(__float_as_int(x), i));
}

// dense self-loop: out[v] = h[v] @ W_self, all nodes
__global__ __launch_bounds__(256, 8) void k_self(
    const float* __restrict__ h, const float* __restrict__ wself,
    float* __restrict__ out)
{
    __shared__ float lds_ws[D * D];
    for (int t = threadIdx.x; t < D * D / 4; t += 256)
        reinterpret_cast<float4*>(lds_ws)[t] = reinterpret_cast<const float4*>(wself)[t];
    __syncthreads();

    const int lane = threadIdx.x & 63;
    const int wave = threadIdx.x >> 6;
    const int base = blockIdx.x * SELF_NPB;

    for (int t = 0; t < SELF_NPB / 16; ++t) {
        const int g = base + t * 16 + wave * 4;   // first of 4 nodes

        int v[4];
        #pragma unroll
        for (int j = 0; j < 4; ++j) v[j] = min(g + j, NN - 1);

        float hv[4];
        #pragma unroll
        for (int j = 0; j < 4; ++j) hv[j] = h[(size_t)v[j] * D + lane];

        float acc[4] = {0.f, 0.f, 0.f, 0.f};
        #pragma unroll
        for (int i = 0; i < D; ++i) {
            const float ws = lds_ws[i * D + lane];
            #pragma unroll
            for (int j = 0; j < 4; ++j)
                acc[j] = fmaf(bcast(hv[j], i), ws, acc[j]);
        }

        #pragma unroll
        for (int j = 0; j < 4; ++j)
            if (g + j < NN) out[(size_t)(g + j) * D + lane] = acc[j];
    }
}

// relation-bucketed agg: out[v] += h[src(v)] @ W[rel(v)]
__global__ __launch_bounds__(256, 8) void k_rel(
    const float* __restrict__ h, const float* __restrict__ weight,
    const u64* __restrict__ packed, float* __restrict__ out)
{
    __shared__ float lds_w[D * D];      // 16 KiB
    __shared__ unsigned lds_list[LCAP];
    __shared__ int lds_cnt;

    const int lane = threadIdx.x & 63;
    const int wave = threadIdx.x >> 6;
    const int r = blockIdx.x / BPR;
    const int start = (blockIdx.x % BPR) * NPB;
    const int count = min(NPB, NN - start);

    if (threadIdx.x == 0) lds_cnt = 0;
    const float4* wsrc = reinterpret_cast<const float4*>(weight + (size_t)r * D * D);
    for (int t = threadIdx.x; t < D * D / 4; t += 256)
        reinterpret_cast<float4*>(lds_w)[t] = wsrc[t];
    __syncthreads();

    for (int t = threadIdx.x; t < count; t += 256) {
        int v = start + t;
        u64 key = packed[v];
        if (key && (int)((key >> 16) & 63) == r) {
            int p = atomicAdd(&lds_cnt, 1);
            if (p < LCAP) lds_list[p] = ((unsigned)v << 16) | (unsigned)(key & 0xFFFF);
        }
    }
    __syncthreads();
    const int cnt = min(lds_cnt, LCAP);

    for (int gi = wave; gi * 4 < cnt; gi += 4) {
        const int g = gi * 4;
        const int nact = min(4, cnt - g);

        int v[4], s[4];
        #pragma unroll
        for (int j = 0; j < 4; ++j) {
            unsigned ent = lds_list[(j < nact) ? (g + j) : g];
            v[j] = (int)(ent >> 16);
            s[j] = (int)(ent & 0xFFFF);
        }

        float hs[4];
        #pragma unroll
        for (int j = 0; j < 4; ++j) hs[j] = h[(size_t)s[j] * D + lane];

        float acc[4] = {0.f, 0.f, 0.f, 0.f};
        #pragma unroll
        for (int i = 0; i < D; ++i) {
            const float w = lds_w[i * D + lane];
            #pragma unroll
            for (int j = 0; j < 4; ++j)
                acc[j] = fmaf(bcast(hs[j], i), w, acc[j]);
        }

        // single writer per node across the whole k_rel grid
        #pragma unroll
        for (int j = 0; j < 4; ++j)
            if (j < nact) {
                size_t o = (size_t)v[j] * D + lane;
                out[o] += acc[j];
            }
    }
}

extern "C" void kernel_launch(void* const* d_in, const int* in_sizes, int n_in,
                              void* d_out, int out_size, void* d_ws, size_t ws_size,
                              hipStream_t stream) {
    const float* h      = (const float*)d_in[0];
    const int*   edges  = (const int*)d_in[1];
    const float* weight = (const float*)d_in[2];
    const float* wself  = (const float*)d_in[3];
    float* out = (float*)d_out;

    u64* packed = (u64*)d_ws;   // NN * 8 B = 400 KB

    k_init<<<(NN / 2 + 255) / 256, 256, 0, stream>>>(packed);
    k_scatter<<<(NE + 255) / 256, 256, 0, stream>>>(edges, packed);
    k_self<<<(NN + SELF_NPB - 1) / SELF_NPB, 256, 0, stream>>>(h, wself, out);
    k_rel<<<NREL * BPR, 256, 0, stream>>>(h, weight, packed, out);
}